// Round 7
// baseline (710.978 us; speedup 1.0000x reference)
//
#include <hip/hip_runtime.h>
#include <math.h>

typedef __bf16 bf16x8 __attribute__((ext_vector_type(8)));
typedef float f32x4 __attribute__((ext_vector_type(4)));
typedef unsigned short ushort8 __attribute__((ext_vector_type(8)));

__device__ __forceinline__ float bf2f(unsigned short u) {
  union { unsigned int i; float f; } c; c.i = ((unsigned int)u) << 16; return c.f;
}
__device__ __forceinline__ unsigned short f2bf(float f) {
  union { float f; unsigned int i; } c; c.f = f;
  unsigned int r = (c.i + 0x7fffu + ((c.i >> 16) & 1u)) >> 16;
  return (unsigned short)r;
}

// ---------------- init: zero bias buffer, deg = 1 (self loop) ----------------
__global__ void zero_k(float* __restrict__ statz, int nz, int* __restrict__ deg, int n) {
  int i = blockIdx.x * blockDim.x + threadIdx.x;
  if (i < nz) statz[i] = 0.f;
  if (i < n) deg[i] = 1;
}

__global__ void deg_count_k(const int* __restrict__ dst, int* __restrict__ deg, int e) {
  int i = blockIdx.x * blockDim.x + threadIdx.x;
  if (i < e) atomicAdd(&deg[dst[i]], 1);
}

__global__ void scan_k(const int* __restrict__ deg, int* __restrict__ offsets,
                       int* __restrict__ cursor, int n) {
  __shared__ int sums[1024];
  int tid = threadIdx.x;
  int chunk = (n + 1023) >> 10;
  int base = tid * chunk;
  int s = 0;
  for (int i = 0; i < chunk; ++i) {
    int j = base + i;
    if (j < n) s += deg[j];
  }
  sums[tid] = s;
  __syncthreads();
  for (int off = 1; off < 1024; off <<= 1) {
    int v = (tid >= off) ? sums[tid - off] : 0;
    __syncthreads();
    sums[tid] += v;
    __syncthreads();
  }
  int run = sums[tid] - s;
  for (int i = 0; i < chunk; ++i) {
    int j = base + i;
    if (j < n) {
      offsets[j] = run;
      cursor[j] = run;
      run += deg[j];
    }
  }
  if (tid == 1023) offsets[n] = sums[1023];
}

__global__ void csr_fill_k(const int* __restrict__ src, const int* __restrict__ dst,
                           int* __restrict__ cursor, int* __restrict__ csr_src,
                           int e, int n) {
  int i = blockIdx.x * blockDim.x + threadIdx.x;
  if (i >= e + n) return;
  int s, d;
  if (i < e) { s = src[i]; d = dst[i]; }
  else       { s = i - e;  d = s; }
  int pos = atomicAdd(&cursor[d], 1);
  csr_src[pos] = s;
}

// ---------------- fused BN0 stats + fp32->bf16 raw convert (coalesced) ----
__global__ __launch_bounds__(256)
void stats_convert_k(const float* __restrict__ x, unsigned short* __restrict__ Abf,
                     float* __restrict__ P1, float* __restrict__ P2,
                     int M, int K, int Kp) {
  int c = blockIdx.x * 256 + threadIdx.x;
  if (c >= Kp) return;
  int rows = (M + gridDim.y - 1) / gridDim.y;
  int r0 = blockIdx.y * rows;
  int r1 = min(M, r0 + rows);
  if (c >= K) {  // zero pad columns
    for (int r = r0; r < r1; ++r) Abf[(size_t)r * Kp + c] = 0;
    return;
  }
  float a = 0.f, b = 0.f;
  int r = r0;
  for (; r + 4 <= r1; r += 4) {
    float v0 = x[(size_t)(r + 0) * K + c];
    float v1 = x[(size_t)(r + 1) * K + c];
    float v2 = x[(size_t)(r + 2) * K + c];
    float v3 = x[(size_t)(r + 3) * K + c];
    a += v0 + v1 + v2 + v3;
    b += v0 * v0 + v1 * v1 + v2 * v2 + v3 * v3;
    Abf[(size_t)(r + 0) * Kp + c] = f2bf(v0);
    Abf[(size_t)(r + 1) * Kp + c] = f2bf(v1);
    Abf[(size_t)(r + 2) * Kp + c] = f2bf(v2);
    Abf[(size_t)(r + 3) * Kp + c] = f2bf(v3);
  }
  for (; r < r1; ++r) {
    float v = x[(size_t)r * K + c];
    a += v; b += v * v;
    Abf[(size_t)r * Kp + c] = f2bf(v);
  }
  P1[(size_t)blockIdx.y * Kp + c] = a;
  P2[(size_t)blockIdx.y * Kp + c] = b;
}

// ---------------- bf16 column stats -> partials ----------------
__global__ __launch_bounds__(256)
void col_stats_bf_k(const unsigned short* __restrict__ h, int M, int D,
                    float* __restrict__ P1, float* __restrict__ P2) {
  int c = blockIdx.x * 256 + threadIdx.x;
  if (c >= D) return;
  int rows = (M + gridDim.y - 1) / gridDim.y;
  int r0 = blockIdx.y * rows;
  int r1 = min(M, r0 + rows);
  float a = 0.f, b = 0.f;
  int r = r0;
  for (; r + 4 <= r1; r += 4) {
    float v0 = bf2f(h[(size_t)(r + 0) * D + c]);
    float v1 = bf2f(h[(size_t)(r + 1) * D + c]);
    float v2 = bf2f(h[(size_t)(r + 2) * D + c]);
    float v3 = bf2f(h[(size_t)(r + 3) * D + c]);
    a += v0 + v1 + v2 + v3;
    b += v0 * v0 + v1 * v1 + v2 * v2 + v3 * v3;
  }
  for (; r < r1; ++r) {
    float v = bf2f(h[(size_t)r * D + c]);
    a += v; b += v * v;
  }
  P1[(size_t)blockIdx.y * D + c] = a;
  P2[(size_t)blockIdx.y * D + c] = b;
}

// ---------------- reduce partials -> BN coefficients a,c ----------------
__global__ __launch_bounds__(256)
void coef_k(const float* __restrict__ P1, const float* __restrict__ P2,
            const float* __restrict__ g, const float* __restrict__ b,
            float* __restrict__ outA, float* __restrict__ outC,
            int K, int Kp, int ny, float invM) {
  int cc = threadIdx.x & 63;
  int c = blockIdx.x * 64 + cc;
  int yl = threadIdx.x >> 6;  // 0..3
  __shared__ float red[2][4][64];
  float s1 = 0.f, s2 = 0.f;
  if (c < Kp) {
#pragma unroll 4
    for (int y = yl; y < ny; y += 4) {
      s1 += P1[(size_t)y * Kp + c];
      s2 += P2[(size_t)y * Kp + c];
    }
  }
  red[0][yl][cc] = s1;
  red[1][yl][cc] = s2;
  __syncthreads();
  if (yl == 0 && c < Kp) {
    s1 = red[0][0][cc] + red[0][1][cc] + red[0][2][cc] + red[0][3][cc];
    s2 = red[1][0][cc] + red[1][1][cc] + red[1][2][cc] + red[1][3][cc];
    if (c >= K) { outA[c] = 0.f; outC[c] = 0.f; return; }
    float m = s1 * invM;
    float var = fmaxf(s2 * invM - m * m, 0.f);
    float a = rsqrtf(var + 1e-5f) * g[c];
    outA[c] = a;
    outC[c] = b[c] - m * a;
  }
}

// BN apply + ReLU fused, bf16 -> bf16, using precomputed a,c
__global__ __launch_bounds__(256)
void bn_apply8_k(const unsigned short* __restrict__ h,
                 const float* __restrict__ aC, const float* __restrict__ cC,
                 unsigned short* __restrict__ outb, size_t total, int D) {
  size_t i = ((size_t)blockIdx.x * 256 + threadIdx.x) * 8;
  if (i >= total) return;
  ushort8 u = *(const ushort8*)(h + i);
  int c = (int)(i % (size_t)D);
  ushort8 o;
#pragma unroll
  for (int j = 0; j < 8; ++j) {
    float v = bf2f(u[j]) * aC[c + j] + cC[c + j];
    o[j] = f2bf(fmaxf(v, 0.f));
  }
  *(ushort8*)(outb + i) = o;
}

// weight transpose-convert for an l/r PAIR via blockIdx.z:
// W [K,N] fp32 -> WT[z*N .. ][N,Kp] bf16, zero pad, optional row scale coefA[k].
__global__ __launch_bounds__(256)
void wconv_pair_k(const float* __restrict__ Wl, const float* __restrict__ Wr,
                  unsigned short* __restrict__ WT, int K, int N, int Kp,
                  const float* __restrict__ coefA) {
  const float* W = blockIdx.z ? Wr : Wl;
  unsigned short* WTo = WT + (size_t)blockIdx.z * N * Kp;
  __shared__ float t[32][33];
  int n0 = blockIdx.x * 32, k0 = blockIdx.y * 32;
  int tx = threadIdx.x & 31, ty = threadIdx.x >> 5;  // 32 x 8
#pragma unroll
  for (int i = 0; i < 32; i += 8) {
    int k = k0 + ty + i, nn = n0 + tx;
    float v = (k < K && nn < N) ? W[(size_t)k * N + nn] : 0.f;
    t[ty + i][tx] = v;
  }
  float ascale = 1.f;
  if (coefA) {
    int k = k0 + tx;
    ascale = (k < Kp) ? coefA[k] : 0.f;
  }
  __syncthreads();
#pragma unroll
  for (int i = 0; i < 32; i += 8) {
    int nn = n0 + ty + i, k = k0 + tx;
    if (nn < N && k < Kp) {
      WTo[(size_t)nn * Kp + k] = f2bf(t[tx][ty + i] * ascale);
    }
  }
}

// bias fold GEMV: bias[col] += sum_k coefC[k] * W[k, col%N]
__global__ __launch_bounds__(256)
void bias_fold_k(const float* __restrict__ Wl, const float* __restrict__ Wr,
                 const float* __restrict__ coefC, float* __restrict__ bias,
                 int K, int N, int KCH) {
  int col = blockIdx.x * 256 + threadIdx.x;
  if (col >= 2 * N) return;
  const float* W = (col >= N) ? Wr : Wl;
  int nn = (col >= N) ? col - N : col;
  int k0 = blockIdx.y * KCH;
  int k1 = min(K, k0 + KCH);
  float s = 0.f;
  int k = k0;
#pragma unroll 8
  for (; k + 8 <= k1; k += 8) {
    s = fmaf(coefC[k + 0], W[(size_t)(k + 0) * N + nn], s);
    s = fmaf(coefC[k + 1], W[(size_t)(k + 1) * N + nn], s);
    s = fmaf(coefC[k + 2], W[(size_t)(k + 2) * N + nn], s);
    s = fmaf(coefC[k + 3], W[(size_t)(k + 3) * N + nn], s);
    s = fmaf(coefC[k + 4], W[(size_t)(k + 4) * N + nn], s);
    s = fmaf(coefC[k + 5], W[(size_t)(k + 5) * N + nn], s);
    s = fmaf(coefC[k + 6], W[(size_t)(k + 6) * N + nn], s);
    s = fmaf(coefC[k + 7], W[(size_t)(k + 7) * N + nn], s);
  }
  for (; k < k1; ++k) s = fmaf(coefC[k], W[(size_t)k * N + nn], s);
  atomicAdd(&bias[col], s);
}

// ---------------- round-4 2-phase dbuf GEMM (BK=64) — used for layers 2-4 ----------
// (measured-best structure for the small-K layers; verbatim from round 4)
template <int BMT>
__global__ __launch_bounds__(512, 2)
void gemm256_k(const unsigned short* __restrict__ A,
               const unsigned short* __restrict__ Bt,
               unsigned short* __restrict__ outL, unsigned short* __restrict__ outR,
               const float* __restrict__ bias, int M, int Nh, int K) {
  constexpr int MF = BMT / 32;
  constexpr int SA = (BMT * 8) / 512;
  constexpr int SB = 4;
  __shared__ unsigned short sA[2][BMT * 64];
  __shared__ unsigned short sB[2][256 * 64];
  const int tid = threadIdx.x;
  const int wave = tid >> 6, lane = tid & 63;
  const int wm = wave >> 2, wn = wave & 3;
  const int l16 = lane & 15, l4 = lane >> 4;

  int nwg = gridDim.x * gridDim.y;
  int bid = blockIdx.y * gridDim.x + blockIdx.x;
  int q = nwg >> 3, r8 = nwg & 7;
  int xcd = bid & 7, ord = bid >> 3;
  int swz = (xcd < r8 ? xcd * (q + 1) : r8 * (q + 1) + (xcd - r8) * q) + ord;
  int bx = swz % gridDim.x, by = swz / gridDim.x;
  const int row0 = by * BMT, col0 = bx * 256;
  const int NT = K >> 6;

  f32x4 acc[MF][4] = {};

  auto stage = [&](int t, int b) {
    int kt = t << 6;
#pragma unroll
    for (int i = 0; i < SA; ++i) {
      int slot = i * 512 + tid;
      int r = slot >> 3;
      int g = (slot & 7) ^ (r & 7);
      int ra = row0 + r; ra = ra < M ? ra : M - 1;
      const unsigned short* ga = A + (size_t)ra * K + kt + g * 8;
      __builtin_amdgcn_global_load_lds(
          (const __attribute__((address_space(1))) void*)ga,
          (__attribute__((address_space(3))) void*)&sA[b][slot * 8], 16, 0, 0);
    }
#pragma unroll
    for (int i = 0; i < SB; ++i) {
      int slot = i * 512 + tid;
      int r = slot >> 3;
      int g = (slot & 7) ^ (r & 7);
      const unsigned short* gb = Bt + (size_t)(col0 + r) * K + kt + g * 8;
      __builtin_amdgcn_global_load_lds(
          (const __attribute__((address_space(1))) void*)gb,
          (__attribute__((address_space(3))) void*)&sB[b][slot * 8], 16, 0, 0);
    }
  };

  stage(0, 0);
  if (NT > 1) stage(1, 1);
  if constexpr (BMT == 256) asm volatile("s_waitcnt vmcnt(8)" ::: "memory");
  else                      asm volatile("s_waitcnt vmcnt(6)" ::: "memory");
  __builtin_amdgcn_sched_barrier(0);
  __builtin_amdgcn_s_barrier();

  int cur = 0;
  for (int t = 0; t < NT; ++t) {
#pragma unroll
    for (int s = 0; s < 2; ++s) {
      bf16x8 afr[MF], bfr[4];
#pragma unroll
      for (int i = 0; i < MF; ++i) {
        int rl = wm * (BMT / 2) + i * 16 + l16;
        int g = s * 4 + l4;
        afr[i] = *(const bf16x8*)&sA[cur][rl * 64 + ((g ^ (rl & 7)) << 3)];
      }
#pragma unroll
      for (int j = 0; j < 4; ++j) {
        int rl = wn * 64 + j * 16 + l16;
        int g = s * 4 + l4;
        bfr[j] = *(const bf16x8*)&sB[cur][rl * 64 + ((g ^ (rl & 7)) << 3)];
      }
      __builtin_amdgcn_s_setprio(1);
#pragma unroll
      for (int i = 0; i < MF; ++i)
#pragma unroll
        for (int j = 0; j < 4; ++j)
          acc[i][j] = __builtin_amdgcn_mfma_f32_16x16x32_bf16(afr[i], bfr[j], acc[i][j], 0, 0, 0);
      __builtin_amdgcn_s_setprio(0);
    }
    if (t + 1 == NT) break;
    __builtin_amdgcn_s_barrier();
    if (t + 2 < NT) {
      stage(t + 2, cur);
      if constexpr (BMT == 256) asm volatile("s_waitcnt vmcnt(8)" ::: "memory");
      else                      asm volatile("s_waitcnt vmcnt(6)" ::: "memory");
    } else {
      asm volatile("s_waitcnt vmcnt(0)" ::: "memory");
    }
    __builtin_amdgcn_sched_barrier(0);
    __builtin_amdgcn_s_barrier();
    cur ^= 1;
  }

#pragma unroll
  for (int i = 0; i < MF; ++i) {
#pragma unroll
    for (int j = 0; j < 4; ++j) {
      int col = col0 + wn * 64 + j * 16 + l16;
      float bv = bias ? bias[col] : 0.f;
      unsigned short* base; int cc;
      if (col < Nh) { base = outL; cc = col; }
      else          { base = outR; cc = col - Nh; }
      int rb = row0 + wm * (BMT / 2) + i * 16 + l4 * 4;
#pragma unroll
      for (int r = 0; r < 4; ++r) {
        int rr = rb + r;
        if (rr < M) base[(size_t)rr * Nh + cc] = f2bf(acc[i][j][r] + bv);
      }
    }
  }
}

// ---------------- 8-phase counted-vmcnt GEMM (m201 template port) — layer 1 --------
// 256x256 tile, BK=64, 512 thr = 8 waves (2M x 4N), wave tile 128x64.
// LDS: [dbuf][A|B][half] 16KB regions, XOR-granule swizzle, inverse perm on the
// global source (rule 21). 8 phases per 2 K-tiles; vmcnt(4) only at phases 3/7.
// Round-6 fix: XCD-chunked bijective block swizzle (m204) restored — each XCD
// owns 4 contiguous row-panels x all col-panels, so the counted waits see
// L2/L3-hit latency instead of HBM latency. Requires K % 128 == 0.
__global__ __launch_bounds__(512, 2)
void gemm8p_k(const unsigned short* __restrict__ A,
              const unsigned short* __restrict__ Bt,
              unsigned short* __restrict__ outL, unsigned short* __restrict__ outR,
              const float* __restrict__ bias, int M, int Nh, int K) {
  __shared__ unsigned short lds[2][2][2][128 * 64];  // [dbuf][mat:0=A,1=B][half]
  const int tid = threadIdx.x;
  const int wave = tid >> 6, lane = tid & 63;
  const int wm = wave >> 2, wn = wave & 3;
  const int l16 = lane & 15, l4 = lane >> 4;

  // bijective XCD-chunked swizzle (m204), row-major tile order
  int nwg = gridDim.x * gridDim.y;
  int bid = blockIdx.y * gridDim.x + blockIdx.x;
  int qd = nwg >> 3, r8 = nwg & 7;
  int xcd = bid & 7, ord = bid >> 3;
  int swz = (xcd < r8 ? xcd * (qd + 1) : r8 * (qd + 1) + (xcd - r8) * qd) + ord;
  int bx = swz % gridDim.x, by = swz / gridDim.x;
  const int row0 = by * 256, col0 = bx * 256;
  const int NT = K >> 6, NI = NT >> 1;

  f32x4 acc[8][4] = {};
  bf16x8 Bfr[4][2];

  auto stageH = [&](int T, int d, int mat, int h) {
    int kt = (T < NT ? T : NT - 1) << 6;
    const unsigned short* base = mat ? Bt : A;
    int r0g = mat ? col0 : row0;
#pragma unroll
    for (int it = 0; it < 2; ++it) {
      int slot = it * 512 + tid;
      int rw = slot >> 3, g = slot & 7;
      int gr = r0g + h * 128 + rw;
      if (!mat) gr = gr < M ? gr : M - 1;
      const unsigned short* gp = base + (size_t)gr * K + kt + ((g ^ (rw & 7)) << 3);
      __builtin_amdgcn_global_load_lds(
          (const __attribute__((address_space(1))) void*)gp,
          (__attribute__((address_space(3))) void*)&lds[d][mat][h][slot * 8], 16, 0, 0);
    }
  };
  auto dsA = [&](int d, int q, bf16x8 (&Afr)[2][2]) {
#pragma unroll
    for (int mi = 0; mi < 2; ++mi)
#pragma unroll
      for (int ks = 0; ks < 2; ++ks) {
        int rw = (2 * q + mi) * 16 + l16;        // row within the wave's half
        int g = ks * 4 + l4;
        Afr[mi][ks] = *(const bf16x8*)&lds[d][0][wm][rw * 64 + ((g ^ (rw & 7)) << 3)];
      }
  };
  auto dsB = [&](int d) {
#pragma unroll
    for (int j = 0; j < 4; ++j)
#pragma unroll
      for (int ks = 0; ks < 2; ++ks) {
        int rl = wn * 64 + j * 16 + l16;
        int rw = rl & 127, h = rl >> 7;
        int g = ks * 4 + l4;
        Bfr[j][ks] = *(const bf16x8*)&lds[d][1][h][rw * 64 + ((g ^ (rw & 7)) << 3)];
      }
  };
  auto mfmaQ = [&](int q, bf16x8 (&Afr)[2][2]) {
    __builtin_amdgcn_s_setprio(1);
#pragma unroll
    for (int mi = 0; mi < 2; ++mi)
#pragma unroll
      for (int j = 0; j < 4; ++j)
#pragma unroll
        for (int ks = 0; ks < 2; ++ks)
          acc[2 * q + mi][j] = __builtin_amdgcn_mfma_f32_16x16x32_bf16(
              Afr[mi][ks], Bfr[j][ks], acc[2 * q + mi][j], 0, 0, 0);
    __builtin_amdgcn_s_setprio(0);
  };

  // prologue: tile0 (A,B)->dbuf0, B(1)->dbuf1.B ; drain to tile0 complete
  stageH(0, 0, 0, 0); stageH(0, 0, 0, 1);
  stageH(0, 0, 1, 0); stageH(0, 0, 1, 1);
  stageH(1, 1, 1, 0); stageH(1, 1, 1, 1);
  asm volatile("s_waitcnt vmcnt(4)" ::: "memory");
  __builtin_amdgcn_sched_barrier(0);
  __builtin_amdgcn_s_barrier();

  for (int i = 0; i < NI; ++i) {
    int T1 = 2 * i + 1, T2 = 2 * i + 2, T3 = 2 * i + 3;
    bf16x8 Afr[2][2];
#pragma unroll
    for (int p = 0; p < 8; ++p) {
      int d = p >> 2;                 // 0: tile 2i from dbuf0, 1: tile 2i+1 from dbuf1
      int qq = p & 3;
      if (qq == 0) dsB(d);
      dsA(d, qq, Afr);
      switch (p) {                    // stage one half-tile into a freed region
        case 0: stageH(T1, 1, 0, 0); break;
        case 1: stageH(T1, 1, 0, 1); break;
        case 2: stageH(T2, 0, 1, 0); break;
        case 3: stageH(T2, 0, 1, 1); break;
        case 4: stageH(T2, 0, 0, 0); break;
        case 5: stageH(T2, 0, 0, 1); break;
        case 6: stageH(T3, 1, 1, 0); break;
        case 7: stageH(T3, 1, 1, 1); break;
      }
      __builtin_amdgcn_s_barrier();
      asm volatile("s_waitcnt lgkmcnt(0)" ::: "memory");
      __builtin_amdgcn_sched_barrier(0);
      mfmaQ(qq, Afr);
      if (p == 3 || p == 7) {
        asm volatile("s_waitcnt vmcnt(4)" ::: "memory");
        __builtin_amdgcn_sched_barrier(0);
      }
      __builtin_amdgcn_s_barrier();
    }
  }

  // epilogue: write C (+bias), split at Nh into outL/outR
#pragma unroll
  for (int i = 0; i < 8; ++i) {
#pragma unroll
    for (int j = 0; j < 4; ++j) {
      int col = col0 + wn * 64 + j * 16 + l16;
      float bv = bias ? bias[col] : 0.f;
      unsigned short* base; int cc;
      if (col < Nh) { base = outL; cc = col; }
      else          { base = outR; cc = col - Nh; }
      int rb = row0 + wm * 128 + i * 16 + l4 * 4;
#pragma unroll
      for (int r = 0; r < 4; ++r) {
        int rr = rb + r;
        if (rr < M) base[(size_t)rr * Nh + cc] = f2bf(acc[i][j][r] + bv);
      }
    }
  }
}

// ---------------- Fused GATv2 edge kernel, depth-3 pipelined gathers ----------------
template <int H>
__global__ __launch_bounds__(256)
void gat_edge_k(const unsigned short* __restrict__ xl, const unsigned short* __restrict__ xr,
                const float* __restrict__ att, const float* __restrict__ bias,
                const int* __restrict__ csr, const int* __restrict__ offsets,
                unsigned short* __restrict__ out, int n, int relu) {
  int gw = (blockIdx.x * 256 + threadIdx.x) >> 6;
  int lane = threadIdx.x & 63;
  if (gw >= n * H) return;
  int node, head;
  if (H == 1) { node = gw; head = 0; }
  else        { node = gw >> 1; head = gw & 1; }
  const int W = H * 512;
  const size_t rowoff = (size_t)node * W + head * 512;
  const size_t choff = (size_t)head * 512 + (size_t)(lane * 8);

  float xrv[8], atv[8];
  {
    ushort8 u = *(const ushort8*)(xr + rowoff + lane * 8);
    const float* ap = att + head * 512 + lane * 8;
#pragma unroll
    for (int j = 0; j < 8; ++j) { xrv[j] = bf2f(u[j]); atv[j] = ap[j]; }
  }
  int p0 = offsets[node], p1 = offsets[node + 1];
  ushort8 u0 = *(const ushort8*)(xl + (size_t)csr[p0] * W + choff);
  ushort8 u1 = u0, u2 = u0;
  if (p0 + 1 < p1) u1 = *(const ushort8*)(xl + (size_t)csr[p0 + 1] * W + choff);
  if (p0 + 2 < p1) u2 = *(const ushort8*)(xl + (size_t)csr[p0 + 2] * W + choff);

  float m = -1e30f, l = 0.f;
  float acc[8];
#pragma unroll
  for (int j = 0; j < 8; ++j) acc[j] = 0.f;
  for (int p = p0; p < p1; ++p) {
    ushort8 u = u0;
    u0 = u1; u1 = u2;
    if (p + 3 < p1) u2 = *(const ushort8*)(xl + (size_t)csr[p + 3] * W + choff);
    float lv[8];
    float e = 0.f;
#pragma unroll
    for (int j = 0; j < 8; ++j) {
      lv[j] = bf2f(u[j]);
      float z = lv[j] + xrv[j];
      z = fmaxf(z, 0.f) + 0.2f * fminf(z, 0.f);
      e = fmaf(z, atv[j], e);
    }
#pragma unroll
    for (int off = 32; off > 0; off >>= 1) e += __shfl_xor(e, off, 64);
    float mn = fmaxf(m, e);
    float corr = __expf(m - mn);
    float w = __expf(e - mn);
    l = l * corr + w;
#pragma unroll
    for (int j = 0; j < 8; ++j) acc[j] = acc[j] * corr + w * lv[j];
    m = mn;
  }
  float inv = 1.f / (l * (float)(p1 - p0));
  const float* bp = bias + head * 512 + lane * 8;
  ushort8 o;
#pragma unroll
  for (int j = 0; j < 8; ++j) {
    float v = acc[j] * inv + bp[j];
    if (relu) v = fmaxf(v, 0.f);
    o[j] = f2bf(v);
  }
  *(ushort8*)(out + rowoff + lane * 8) = o;
}

// ---------------- fused head + gather: out = sigmoid(h[tidx]@Wh+bh), y[tidx] --------
__global__ void head_gather_k(const unsigned short* __restrict__ h, const float* __restrict__ Wh,
                   const float* __restrict__ bh, const float* __restrict__ y,
                   const int* __restrict__ tidx, float* __restrict__ out, int nt) {
  int gw = (blockIdx.x * 256 + threadIdx.x) >> 6;
  int lane = threadIdx.x & 63;
  if (gw >= nt) return;
  int j = tidx[gw];
  ushort8 u = *(const ushort8*)(h + (size_t)j * 512 + lane * 8);
  const float* wp = Wh + lane * 8;
  float s = 0.f;
#pragma unroll
  for (int q = 0; q < 8; ++q) s = fmaf(bf2f(u[q]), wp[q], s);
#pragma unroll
  for (int off = 32; off > 0; off >>= 1) s += __shfl_xor(s, off, 64);
  if (lane == 0) {
    out[gw] = 1.f / (1.f + __expf(-(s + bh[0])));
    out[nt + gw] = y[j];
  }
}

// ---------------- launch ----------------
extern "C" void kernel_launch(void* const* d_in, const int* in_sizes, int n_in,
                              void* d_out, int out_size, void* d_ws, size_t ws_size,
                              hipStream_t stream) {
  const float* x     = (const float*)d_in[0];
  const int*   ei    = (const int*)d_in[1];
  const float* y     = (const float*)d_in[2];
  const int*   tidx  = (const int*)d_in[3];
  const float* bn0_g = (const float*)d_in[4];
  const float* bn0_b = (const float*)d_in[5];
  const float* W1l   = (const float*)d_in[6];
  const float* W1r   = (const float*)d_in[7];
  const float* a1    = (const float*)d_in[8];
  const float* b1    = (const float*)d_in[9];
  const float* bn1_g = (const float*)d_in[10];
  const float* bn1_b = (const float*)d_in[11];
  const float* W2l   = (const float*)d_in[12];
  const float* W2r   = (const float*)d_in[13];
  const float* a2    = (const float*)d_in[14];
  const float* b2    = (const float*)d_in[15];
  const float* bn2_g = (const float*)d_in[16];
  const float* bn2_b = (const float*)d_in[17];
  const float* W3l   = (const float*)d_in[18];
  const float* W3r   = (const float*)d_in[19];
  const float* a3    = (const float*)d_in[20];
  const float* b3    = (const float*)d_in[21];
  const float* bn3_g = (const float*)d_in[22];
  const float* bn3_b = (const float*)d_in[23];
  const float* W4l   = (const float*)d_in[24];
  const float* W4r   = (const float*)d_in[25];
  const float* a4    = (const float*)d_in[26];
  const float* b4    = (const float*)d_in[27];
  const float* Wh    = (const float*)d_in[28];
  const float* bh    = (const float*)d_in[29];
  float* out = (float*)d_out;

  const int n   = in_sizes[2];      // 8000
  const int E   = in_sizes[1] / 2;  // 64000
  const int FIN = in_sizes[4];      // 3201
  const int NT  = in_sizes[3];      // 4000
  const int ET  = E + n;
  const int KP1 = 3328;             // pad to 52 K-tiles (even, for 8-phase)
  const int NY0 = 200;              // stats_convert y-blocks
  const int NYS = 160;              // col_stats y-blocks

  // ---- workspace layout ----
  unsigned short* us = (unsigned short*)d_ws;
  const size_t ABF_SZ = (size_t)n * KP1;
  unsigned short* Abf = us;
  unsigned short* hb  = us + ABF_SZ;
  unsigned short* xlb = hb + (size_t)n * 1024;
  unsigned short* xrb = xlb + (size_t)n * 1024;
  float* fp = (float*)(xrb + (size_t)n * 1024);
  float* biasb = fp;           fp += 2048;   // zeroed each launch
  float* coefA = fp;           fp += 3328;   // BN0 fold: row scale
  float* coefC = fp;           fp += 3328;   // BN0 fold: additive const
  float* aC    = fp;           fp += 1024;   // per-layer BN a (reused)
  float* cC    = fp;           fp += 1024;   // per-layer BN c (reused)
  int* deg     = (int*)fp;
  int* offsets = deg + n;
  int* cursor  = offsets + n + 1;
  int* csr     = cursor + n;
  unsigned short* W1T = hb;                          // [2048, KP1] combined Bt
  unsigned short* WT  = Abf + (size_t)n * 1024;      // layers 2-4 combined Bt
  // BN0 stats partials: live in hb region BEFORE wconv writes W1T there.
  float* P0a = (float*)hb;                   // [NY0][KP1]
  float* P0b = P0a + (size_t)NY0 * KP1;
  // BN1-3 stats partials: tail of Abf region (free after layer-1 GEMMs).
  float* Psa = (float*)(Abf + (size_t)n * 1024 + 8ull * 1024 * 1024);
  float* Psb = Psa + (size_t)NYS * 1024;

  // ---- init + CSR build ----
  const int kZeroCount = 2048;
  int zmax = n > kZeroCount ? n : kZeroCount;
  zero_k<<<(zmax + 255) / 256, 256, 0, stream>>>(biasb, kZeroCount, deg, n);
  deg_count_k<<<(E + 255) / 256, 256, 0, stream>>>(ei + E, deg, E);
  scan_k<<<1, 1024, 0, stream>>>(deg, offsets, cursor, n);
  csr_fill_k<<<(ET + 255) / 256, 256, 0, stream>>>(ei, ei + E, cursor, csr, E, n);

  float invM = 1.f / (float)n;

  // ---- BN0: fused stats (partials) + raw bf16 convert (single coalesced pass) ----
  {
    dim3 g((KP1 + 255) / 256, NY0);
    stats_convert_k<<<g, 256, 0, stream>>>(x, Abf, P0a, P0b, n, FIN, KP1);
    coef_k<<<(KP1 + 63) / 64, 256, 0, stream>>>(P0a, P0b, bn0_g, bn0_b,
                                                coefA, coefC, FIN, KP1, NY0, invM);
  }

  // ---- Layer 1 (H=2, K=3328 padded -> 2048 cols merged), BN0 folded -------
  {
    dim3 gw1(1024 / 32, KP1 / 32, 2);
    wconv_pair_k<<<gw1, 256, 0, stream>>>(W1l, W1r, W1T, FIN, 1024, KP1, coefA);
    dim3 gb(8, (FIN + 127) / 128);
    bias_fold_k<<<gb, 256, 0, stream>>>(W1l, W1r, coefC, biasb, FIN, 1024, 128);
    dim3 g(2048 / 256, (n + 255) / 256);   // 8 x 32 = 256 blocks, 1/CU
    gemm8p_k<<<g, 512, 0, stream>>>(Abf, W1T, xlb, xrb, biasb, n, 1024, KP1);
  }
  gat_edge_k<2><<<(n * 2 + 3) / 4, 256, 0, stream>>>(xlb, xrb, a1, b1, csr, offsets, hb, n, 0);
  {
    dim3 g(1024 / 256, NYS);
    col_stats_bf_k<<<g, 256, 0, stream>>>(hb, n, 1024, Psa, Psb);
    coef_k<<<1024 / 64, 256, 0, stream>>>(Psa, Psb, bn1_g, bn1_b, aC, cC, 1024, 1024, NYS, invM);
    bn_apply8_k<<<(int)(((size_t)n * 1024 / 8 + 255) / 256), 256, 0, stream>>>(
        hb, aC, cC, Abf, (size_t)n * 1024, 1024);
  }

  // ---- Layer 2 (K=1024 -> N=1024 combined) ----
  {
    dim3 gw2(512 / 32, 1024 / 32, 2);
    wconv_pair_k<<<gw2, 256, 0, stream>>>(W2l, W2r, WT, 1024, 512, 1024, nullptr);
    dim3 g(1024 / 256, (n + 127) / 128);   // 4 x 63 = 252 blocks
    gemm256_k<128><<<g, 512, 0, stream>>>(Abf, WT, xlb, xrb, nullptr, n, 512, 1024);
  }
  gat_edge_k<1><<<(n + 3) / 4, 256, 0, stream>>>(xlb, xrb, a2, b2, csr, offsets, hb, n, 0);
  {
    dim3 g(512 / 256, NYS);
    col_stats_bf_k<<<g, 256, 0, stream>>>(hb, n, 512, Psa, Psb);
    coef_k<<<512 / 64, 256, 0, stream>>>(Psa, Psb, bn2_g, bn2_b, aC, cC, 512, 512, NYS, invM);
    bn_apply8_k<<<(int)(((size_t)n * 512 / 8 + 255) / 256), 256, 0, stream>>>(
        hb, aC, cC, Abf, (size_t)n * 512, 512);
  }

  // ---- Layer 3 (K=512 -> N=1024 combined) ----
  {
    dim3 gw3(512 / 32, 512 / 32, 2);
    wconv_pair_k<<<gw3, 256, 0, stream>>>(W3l, W3r, WT, 512, 512, 512, nullptr);
    dim3 g(1024 / 256, (n + 127) / 128);
    gemm256_k<128><<<g, 512, 0, stream>>>(Abf, WT, xlb, xrb, nullptr, n, 512, 512);
  }
  gat_edge_k<1><<<(n + 3) / 4, 256, 0, stream>>>(xlb, xrb, a3, b3, csr, offsets, hb, n, 0);
  {
    dim3 g(512 / 256, NYS);
    col_stats_bf_k<<<g, 256, 0, stream>>>(hb, n, 512, Psa, Psb);
    coef_k<<<512 / 64, 256, 0, stream>>>(Psa, Psb, bn3_g, bn3_b, aC, cC, 512, 512, NYS, invM);
    bn_apply8_k<<<(int)(((size_t)n * 512 / 8 + 255) / 256), 256, 0, stream>>>(
        hb, aC, cC, Abf, (size_t)n * 512, 512);
  }

  // ---- Layer 4 (K=512 -> N=1024 combined), relu fused into edge kernel ----
  {
    dim3 gw4(512 / 32, 512 / 32, 2);
    wconv_pair_k<<<gw4, 256, 0, stream>>>(W4l, W4r, WT, 512, 512, 512, nullptr);
    dim3 g(1024 / 256, (n + 127) / 128);
    gemm256_k<128><<<g, 512, 0, stream>>>(Abf, WT, xlb, xrb, nullptr, n, 512, 512);
  }
  gat_edge_k<1><<<(n + 3) / 4, 256, 0, stream>>>(xlb, xrb, a4, b4, csr, offsets, hb, n, 1);

  // ---- fused head + gather (train rows only) ----
  head_gather_k<<<(NT + 3) / 4, 256, 0, stream>>>(hb, Wh, bh, y, tidx, out, NT);
}

// Round 8
// 701.424 us; speedup vs baseline: 1.0136x; 1.0136x over previous
//
#include <hip/hip_runtime.h>
#include <math.h>

typedef __bf16 bf16x8 __attribute__((ext_vector_type(8)));
typedef float f32x4 __attribute__((ext_vector_type(4)));
typedef unsigned short ushort8 __attribute__((ext_vector_type(8)));

__device__ __forceinline__ float bf2f(unsigned short u) {
  union { unsigned int i; float f; } c; c.i = ((unsigned int)u) << 16; return c.f;
}
__device__ __forceinline__ unsigned short f2bf(float f) {
  union { float f; unsigned int i; } c; c.f = f;
  unsigned int r = (c.i + 0x7fffu + ((c.i >> 16) & 1u)) >> 16;
  return (unsigned short)r;
}

// ---------------- init: zero bias buffer, deg = 1 (self loop) ----------------
__global__ void zero_k(float* __restrict__ statz, int nz, int* __restrict__ deg, int n) {
  int i = blockIdx.x * blockDim.x + threadIdx.x;
  if (i < nz) statz[i] = 0.f;
  if (i < n) deg[i] = 1;
}

__global__ void deg_count_k(const int* __restrict__ dst, int* __restrict__ deg, int e) {
  int i = blockIdx.x * blockDim.x + threadIdx.x;
  if (i < e) atomicAdd(&deg[dst[i]], 1);
}

__global__ void scan_k(const int* __restrict__ deg, int* __restrict__ offsets,
                       int* __restrict__ cursor, int n) {
  __shared__ int sums[1024];
  int tid = threadIdx.x;
  int chunk = (n + 1023) >> 10;
  int base = tid * chunk;
  int s = 0;
  for (int i = 0; i < chunk; ++i) {
    int j = base + i;
    if (j < n) s += deg[j];
  }
  sums[tid] = s;
  __syncthreads();
  for (int off = 1; off < 1024; off <<= 1) {
    int v = (tid >= off) ? sums[tid - off] : 0;
    __syncthreads();
    sums[tid] += v;
    __syncthreads();
  }
  int run = sums[tid] - s;
  for (int i = 0; i < chunk; ++i) {
    int j = base + i;
    if (j < n) {
      offsets[j] = run;
      cursor[j] = run;
      run += deg[j];
    }
  }
  if (tid == 1023) offsets[n] = sums[1023];
}

__global__ void csr_fill_k(const int* __restrict__ src, const int* __restrict__ dst,
                           int* __restrict__ cursor, int* __restrict__ csr_src,
                           int e, int n) {
  int i = blockIdx.x * blockDim.x + threadIdx.x;
  if (i >= e + n) return;
  int s, d;
  if (i < e) { s = src[i]; d = dst[i]; }
  else       { s = i - e;  d = s; }
  int pos = atomicAdd(&cursor[d], 1);
  csr_src[pos] = s;
}

// ---------------- fused BN0 stats + fp32->bf16 raw convert (coalesced) ----
__global__ __launch_bounds__(256)
void stats_convert_k(const float* __restrict__ x, unsigned short* __restrict__ Abf,
                     float* __restrict__ P1, float* __restrict__ P2,
                     int M, int K, int Kp) {
  int c = blockIdx.x * 256 + threadIdx.x;
  if (c >= Kp) return;
  int rows = (M + gridDim.y - 1) / gridDim.y;
  int r0 = blockIdx.y * rows;
  int r1 = min(M, r0 + rows);
  if (c >= K) {  // zero pad columns
    for (int r = r0; r < r1; ++r) Abf[(size_t)r * Kp + c] = 0;
    return;
  }
  float a = 0.f, b = 0.f;
  int r = r0;
  for (; r + 4 <= r1; r += 4) {
    float v0 = x[(size_t)(r + 0) * K + c];
    float v1 = x[(size_t)(r + 1) * K + c];
    float v2 = x[(size_t)(r + 2) * K + c];
    float v3 = x[(size_t)(r + 3) * K + c];
    a += v0 + v1 + v2 + v3;
    b += v0 * v0 + v1 * v1 + v2 * v2 + v3 * v3;
    Abf[(size_t)(r + 0) * Kp + c] = f2bf(v0);
    Abf[(size_t)(r + 1) * Kp + c] = f2bf(v1);
    Abf[(size_t)(r + 2) * Kp + c] = f2bf(v2);
    Abf[(size_t)(r + 3) * Kp + c] = f2bf(v3);
  }
  for (; r < r1; ++r) {
    float v = x[(size_t)r * K + c];
    a += v; b += v * v;
    Abf[(size_t)r * Kp + c] = f2bf(v);
  }
  P1[(size_t)blockIdx.y * Kp + c] = a;
  P2[(size_t)blockIdx.y * Kp + c] = b;
}

// ---------------- bf16 column stats -> partials ----------------
__global__ __launch_bounds__(256)
void col_stats_bf_k(const unsigned short* __restrict__ h, int M, int D,
                    float* __restrict__ P1, float* __restrict__ P2) {
  int c = blockIdx.x * 256 + threadIdx.x;
  if (c >= D) return;
  int rows = (M + gridDim.y - 1) / gridDim.y;
  int r0 = blockIdx.y * rows;
  int r1 = min(M, r0 + rows);
  float a = 0.f, b = 0.f;
  int r = r0;
  for (; r + 4 <= r1; r += 4) {
    float v0 = bf2f(h[(size_t)(r + 0) * D + c]);
    float v1 = bf2f(h[(size_t)(r + 1) * D + c]);
    float v2 = bf2f(h[(size_t)(r + 2) * D + c]);
    float v3 = bf2f(h[(size_t)(r + 3) * D + c]);
    a += v0 + v1 + v2 + v3;
    b += v0 * v0 + v1 * v1 + v2 * v2 + v3 * v3;
  }
  for (; r < r1; ++r) {
    float v = bf2f(h[(size_t)r * D + c]);
    a += v; b += v * v;
  }
  P1[(size_t)blockIdx.y * D + c] = a;
  P2[(size_t)blockIdx.y * D + c] = b;
}

// ---------------- reduce partials -> BN coefficients a,c ----------------
__global__ __launch_bounds__(256)
void coef_k(const float* __restrict__ P1, const float* __restrict__ P2,
            const float* __restrict__ g, const float* __restrict__ b,
            float* __restrict__ outA, float* __restrict__ outC,
            int K, int Kp, int ny, float invM) {
  int cc = threadIdx.x & 63;
  int c = blockIdx.x * 64 + cc;
  int yl = threadIdx.x >> 6;  // 0..3
  __shared__ float red[2][4][64];
  float s1 = 0.f, s2 = 0.f;
  if (c < Kp) {
#pragma unroll 4
    for (int y = yl; y < ny; y += 4) {
      s1 += P1[(size_t)y * Kp + c];
      s2 += P2[(size_t)y * Kp + c];
    }
  }
  red[0][yl][cc] = s1;
  red[1][yl][cc] = s2;
  __syncthreads();
  if (yl == 0 && c < Kp) {
    s1 = red[0][0][cc] + red[0][1][cc] + red[0][2][cc] + red[0][3][cc];
    s2 = red[1][0][cc] + red[1][1][cc] + red[1][2][cc] + red[1][3][cc];
    if (c >= K) { outA[c] = 0.f; outC[c] = 0.f; return; }
    float m = s1 * invM;
    float var = fmaxf(s2 * invM - m * m, 0.f);
    float a = rsqrtf(var + 1e-5f) * g[c];
    outA[c] = a;
    outC[c] = b[c] - m * a;
  }
}

// BN apply + ReLU fused, bf16 -> bf16, using precomputed a,c
__global__ __launch_bounds__(256)
void bn_apply8_k(const unsigned short* __restrict__ h,
                 const float* __restrict__ aC, const float* __restrict__ cC,
                 unsigned short* __restrict__ outb, size_t total, int D) {
  size_t i = ((size_t)blockIdx.x * 256 + threadIdx.x) * 8;
  if (i >= total) return;
  ushort8 u = *(const ushort8*)(h + i);
  int c = (int)(i % (size_t)D);
  ushort8 o;
#pragma unroll
  for (int j = 0; j < 8; ++j) {
    float v = bf2f(u[j]) * aC[c + j] + cC[c + j];
    o[j] = f2bf(fmaxf(v, 0.f));
  }
  *(ushort8*)(outb + i) = o;
}

// weight transpose-convert for an l/r PAIR via blockIdx.z:
// W [K,N] fp32 -> WT[z*N .. ][N,Kp] bf16, zero pad, optional row scale coefA[k].
__global__ __launch_bounds__(256)
void wconv_pair_k(const float* __restrict__ Wl, const float* __restrict__ Wr,
                  unsigned short* __restrict__ WT, int K, int N, int Kp,
                  const float* __restrict__ coefA) {
  const float* W = blockIdx.z ? Wr : Wl;
  unsigned short* WTo = WT + (size_t)blockIdx.z * N * Kp;
  __shared__ float t[32][33];
  int n0 = blockIdx.x * 32, k0 = blockIdx.y * 32;
  int tx = threadIdx.x & 31, ty = threadIdx.x >> 5;  // 32 x 8
#pragma unroll
  for (int i = 0; i < 32; i += 8) {
    int k = k0 + ty + i, nn = n0 + tx;
    float v = (k < K && nn < N) ? W[(size_t)k * N + nn] : 0.f;
    t[ty + i][tx] = v;
  }
  float ascale = 1.f;
  if (coefA) {
    int k = k0 + tx;
    ascale = (k < Kp) ? coefA[k] : 0.f;
  }
  __syncthreads();
#pragma unroll
  for (int i = 0; i < 32; i += 8) {
    int nn = n0 + ty + i, k = k0 + tx;
    if (nn < N && k < Kp) {
      WTo[(size_t)nn * Kp + k] = f2bf(t[tx][ty + i] * ascale);
    }
  }
}

// bias fold GEMV: bias[col] += sum_k coefC[k] * W[k, col%N]
__global__ __launch_bounds__(256)
void bias_fold_k(const float* __restrict__ Wl, const float* __restrict__ Wr,
                 const float* __restrict__ coefC, float* __restrict__ bias,
                 int K, int N, int KCH) {
  int col = blockIdx.x * 256 + threadIdx.x;
  if (col >= 2 * N) return;
  const float* W = (col >= N) ? Wr : Wl;
  int nn = (col >= N) ? col - N : col;
  int k0 = blockIdx.y * KCH;
  int k1 = min(K, k0 + KCH);
  float s = 0.f;
  int k = k0;
#pragma unroll 8
  for (; k + 8 <= k1; k += 8) {
    s = fmaf(coefC[k + 0], W[(size_t)(k + 0) * N + nn], s);
    s = fmaf(coefC[k + 1], W[(size_t)(k + 1) * N + nn], s);
    s = fmaf(coefC[k + 2], W[(size_t)(k + 2) * N + nn], s);
    s = fmaf(coefC[k + 3], W[(size_t)(k + 3) * N + nn], s);
    s = fmaf(coefC[k + 4], W[(size_t)(k + 4) * N + nn], s);
    s = fmaf(coefC[k + 5], W[(size_t)(k + 5) * N + nn], s);
    s = fmaf(coefC[k + 6], W[(size_t)(k + 6) * N + nn], s);
    s = fmaf(coefC[k + 7], W[(size_t)(k + 7) * N + nn], s);
  }
  for (; k < k1; ++k) s = fmaf(coefC[k], W[(size_t)k * N + nn], s);
  atomicAdd(&bias[col], s);
}

// ---------------- round-4 2-phase dbuf GEMM (BK=64) — used for layers 2-4 ----------
// (measured-best structure for the small-K layers; verbatim from round 4)
template <int BMT>
__global__ __launch_bounds__(512, 2)
void gemm256_k(const unsigned short* __restrict__ A,
               const unsigned short* __restrict__ Bt,
               unsigned short* __restrict__ outL, unsigned short* __restrict__ outR,
               const float* __restrict__ bias, int M, int Nh, int K) {
  constexpr int MF = BMT / 32;
  constexpr int SA = (BMT * 8) / 512;
  constexpr int SB = 4;
  __shared__ unsigned short sA[2][BMT * 64];
  __shared__ unsigned short sB[2][256 * 64];
  const int tid = threadIdx.x;
  const int wave = tid >> 6, lane = tid & 63;
  const int wm = wave >> 2, wn = wave & 3;
  const int l16 = lane & 15, l4 = lane >> 4;

  int nwg = gridDim.x * gridDim.y;
  int bid = blockIdx.y * gridDim.x + blockIdx.x;
  int q = nwg >> 3, r8 = nwg & 7;
  int xcd = bid & 7, ord = bid >> 3;
  int swz = (xcd < r8 ? xcd * (q + 1) : r8 * (q + 1) + (xcd - r8) * q) + ord;
  int bx = swz % gridDim.x, by = swz / gridDim.x;
  const int row0 = by * BMT, col0 = bx * 256;
  const int NT = K >> 6;

  f32x4 acc[MF][4] = {};

  auto stage = [&](int t, int b) {
    int kt = t << 6;
#pragma unroll
    for (int i = 0; i < SA; ++i) {
      int slot = i * 512 + tid;
      int r = slot >> 3;
      int g = (slot & 7) ^ (r & 7);
      int ra = row0 + r; ra = ra < M ? ra : M - 1;
      const unsigned short* ga = A + (size_t)ra * K + kt + g * 8;
      __builtin_amdgcn_global_load_lds(
          (const __attribute__((address_space(1))) void*)ga,
          (__attribute__((address_space(3))) void*)&sA[b][slot * 8], 16, 0, 0);
    }
#pragma unroll
    for (int i = 0; i < SB; ++i) {
      int slot = i * 512 + tid;
      int r = slot >> 3;
      int g = (slot & 7) ^ (r & 7);
      const unsigned short* gb = Bt + (size_t)(col0 + r) * K + kt + g * 8;
      __builtin_amdgcn_global_load_lds(
          (const __attribute__((address_space(1))) void*)gb,
          (__attribute__((address_space(3))) void*)&sB[b][slot * 8], 16, 0, 0);
    }
  };

  stage(0, 0);
  if (NT > 1) stage(1, 1);
  if constexpr (BMT == 256) asm volatile("s_waitcnt vmcnt(8)" ::: "memory");
  else                      asm volatile("s_waitcnt vmcnt(6)" ::: "memory");
  __builtin_amdgcn_sched_barrier(0);
  __builtin_amdgcn_s_barrier();

  int cur = 0;
  for (int t = 0; t < NT; ++t) {
#pragma unroll
    for (int s = 0; s < 2; ++s) {
      bf16x8 afr[MF], bfr[4];
#pragma unroll
      for (int i = 0; i < MF; ++i) {
        int rl = wm * (BMT / 2) + i * 16 + l16;
        int g = s * 4 + l4;
        afr[i] = *(const bf16x8*)&sA[cur][rl * 64 + ((g ^ (rl & 7)) << 3)];
      }
#pragma unroll
      for (int j = 0; j < 4; ++j) {
        int rl = wn * 64 + j * 16 + l16;
        int g = s * 4 + l4;
        bfr[j] = *(const bf16x8*)&sB[cur][rl * 64 + ((g ^ (rl & 7)) << 3)];
      }
      __builtin_amdgcn_s_setprio(1);
#pragma unroll
      for (int i = 0; i < MF; ++i)
#pragma unroll
        for (int j = 0; j < 4; ++j)
          acc[i][j] = __builtin_amdgcn_mfma_f32_16x16x32_bf16(afr[i], bfr[j], acc[i][j], 0, 0, 0);
      __builtin_amdgcn_s_setprio(0);
    }
    if (t + 1 == NT) break;
    __builtin_amdgcn_s_barrier();
    if (t + 2 < NT) {
      stage(t + 2, cur);
      if constexpr (BMT == 256) asm volatile("s_waitcnt vmcnt(8)" ::: "memory");
      else                      asm volatile("s_waitcnt vmcnt(6)" ::: "memory");
    } else {
      asm volatile("s_waitcnt vmcnt(0)" ::: "memory");
    }
    __builtin_amdgcn_sched_barrier(0);
    __builtin_amdgcn_s_barrier();
    cur ^= 1;
  }

#pragma unroll
  for (int i = 0; i < MF; ++i) {
#pragma unroll
    for (int j = 0; j < 4; ++j) {
      int col = col0 + wn * 64 + j * 16 + l16;
      float bv = bias ? bias[col] : 0.f;
      unsigned short* base; int cc;
      if (col < Nh) { base = outL; cc = col; }
      else          { base = outR; cc = col - Nh; }
      int rb = row0 + wm * (BMT / 2) + i * 16 + l4 * 4;
#pragma unroll
      for (int r = 0; r < 4; ++r) {
        int rr = rb + r;
        if (rr < M) base[(size_t)rr * Nh + cc] = f2bf(acc[i][j][r] + bv);
      }
    }
  }
}

// ---------------- 8-phase counted-vmcnt GEMM — layer 1 -----------------------------
// 256x256 tile, BK=64, 512 thr = 8 waves (2M x 4N), wave tile 128x64.
// LDS: [dbuf][A|B][half] 16KB regions, XOR-granule swizzle, inverse perm on the
// global source (rule 21). 8 phases per 2 K-tiles; vmcnt(4) only at phases 3/7.
// Round-7 change: ONE barrier per phase (was two). Safe because every stage
// target region's last reader is >=1 full phase earlier (P0/P1->d1.A read prev-P4..7;
// P2/P3->d0.B last read P0 (dsB caches all frags in regs); P4/P5->d0.A last read P3;
// P6/P7->d1.B read P4), and phase-lockstep is enforced by the end-of-phase barrier.
// RAW: each wave's vmcnt(4) at P3/P7 precedes its end-of-phase barrier, so all
// waves' DMA for tile t+1 is globally landed before any wave reads it (same
// accounting as the 2-barrier version, verified rounds 5-7). K % 128 == 0.
__global__ __launch_bounds__(512, 2)
void gemm8p_k(const unsigned short* __restrict__ A,
              const unsigned short* __restrict__ Bt,
              unsigned short* __restrict__ outL, unsigned short* __restrict__ outR,
              const float* __restrict__ bias, int M, int Nh, int K) {
  __shared__ unsigned short lds[2][2][2][128 * 64];  // [dbuf][mat:0=A,1=B][half]
  const int tid = threadIdx.x;
  const int wave = tid >> 6, lane = tid & 63;
  const int wm = wave >> 2, wn = wave & 3;
  const int l16 = lane & 15, l4 = lane >> 4;

  // bijective XCD-chunked swizzle (m204), row-major tile order
  int nwg = gridDim.x * gridDim.y;
  int bid = blockIdx.y * gridDim.x + blockIdx.x;
  int qd = nwg >> 3, r8 = nwg & 7;
  int xcd = bid & 7, ord = bid >> 3;
  int swz = (xcd < r8 ? xcd * (qd + 1) : r8 * (qd + 1) + (xcd - r8) * qd) + ord;
  int bx = swz % gridDim.x, by = swz / gridDim.x;
  const int row0 = by * 256, col0 = bx * 256;
  const int NT = K >> 6, NI = NT >> 1;

  f32x4 acc[8][4] = {};
  bf16x8 Bfr[4][2];

  auto stageH = [&](int T, int d, int mat, int h) {
    int kt = (T < NT ? T : NT - 1) << 6;
    const unsigned short* base = mat ? Bt : A;
    int r0g = mat ? col0 : row0;
#pragma unroll
    for (int it = 0; it < 2; ++it) {
      int slot = it * 512 + tid;
      int rw = slot >> 3, g = slot & 7;
      int gr = r0g + h * 128 + rw;
      if (!mat) gr = gr < M ? gr : M - 1;
      const unsigned short* gp = base + (size_t)gr * K + kt + ((g ^ (rw & 7)) << 3);
      __builtin_amdgcn_global_load_lds(
          (const __attribute__((address_space(1))) void*)gp,
          (__attribute__((address_space(3))) void*)&lds[d][mat][h][slot * 8], 16, 0, 0);
    }
  };
  auto dsA = [&](int d, int q, bf16x8 (&Afr)[2][2]) {
#pragma unroll
    for (int mi = 0; mi < 2; ++mi)
#pragma unroll
      for (int ks = 0; ks < 2; ++ks) {
        int rw = (2 * q + mi) * 16 + l16;        // row within the wave's half
        int g = ks * 4 + l4;
        Afr[mi][ks] = *(const bf16x8*)&lds[d][0][wm][rw * 64 + ((g ^ (rw & 7)) << 3)];
      }
  };
  auto dsB = [&](int d) {
#pragma unroll
    for (int j = 0; j < 4; ++j)
#pragma unroll
      for (int ks = 0; ks < 2; ++ks) {
        int rl = wn * 64 + j * 16 + l16;
        int rw = rl & 127, h = rl >> 7;
        int g = ks * 4 + l4;
        Bfr[j][ks] = *(const bf16x8*)&lds[d][1][h][rw * 64 + ((g ^ (rw & 7)) << 3)];
      }
  };
  auto mfmaQ = [&](int q, bf16x8 (&Afr)[2][2]) {
    __builtin_amdgcn_s_setprio(1);
#pragma unroll
    for (int mi = 0; mi < 2; ++mi)
#pragma unroll
      for (int j = 0; j < 4; ++j)
#pragma unroll
        for (int ks = 0; ks < 2; ++ks)
          acc[2 * q + mi][j] = __builtin_amdgcn_mfma_f32_16x16x32_bf16(
              Afr[mi][ks], Bfr[j][ks], acc[2 * q + mi][j], 0, 0, 0);
    __builtin_amdgcn_s_setprio(0);
  };

  // prologue: tile0 (A,B)->dbuf0, B(1)->dbuf1.B ; drain to tile0 complete
  stageH(0, 0, 0, 0); stageH(0, 0, 0, 1);
  stageH(0, 0, 1, 0); stageH(0, 0, 1, 1);
  stageH(1, 1, 1, 0); stageH(1, 1, 1, 1);
  asm volatile("s_waitcnt vmcnt(4)" ::: "memory");
  __builtin_amdgcn_sched_barrier(0);
  __builtin_amdgcn_s_barrier();

  for (int i = 0; i < NI; ++i) {
    int T1 = 2 * i + 1, T2 = 2 * i + 2, T3 = 2 * i + 3;
    bf16x8 Afr[2][2];
#pragma unroll
    for (int p = 0; p < 8; ++p) {
      int d = p >> 2;                 // 0: tile 2i from dbuf0, 1: tile 2i+1 from dbuf1
      int qq = p & 3;
      if (qq == 0) dsB(d);
      dsA(d, qq, Afr);
      switch (p) {                    // stage one half-tile into a freed region
        case 0: stageH(T1, 1, 0, 0); break;
        case 1: stageH(T1, 1, 0, 1); break;
        case 2: stageH(T2, 0, 1, 0); break;
        case 3: stageH(T2, 0, 1, 1); break;
        case 4: stageH(T2, 0, 0, 0); break;
        case 5: stageH(T2, 0, 0, 1); break;
        case 6: stageH(T3, 1, 1, 0); break;
        case 7: stageH(T3, 1, 1, 1); break;
      }
      asm volatile("s_waitcnt lgkmcnt(0)" ::: "memory");
      __builtin_amdgcn_sched_barrier(0);
      mfmaQ(qq, Afr);
      if (p == 3 || p == 7) {
        asm volatile("s_waitcnt vmcnt(4)" ::: "memory");
        __builtin_amdgcn_sched_barrier(0);
      }
      __builtin_amdgcn_s_barrier();   // single end-of-phase barrier
    }
  }

  // epilogue: write C (+bias), split at Nh into outL/outR
#pragma unroll
  for (int i = 0; i < 8; ++i) {
#pragma unroll
    for (int j = 0; j < 4; ++j) {
      int col = col0 + wn * 64 + j * 16 + l16;
      float bv = bias ? bias[col] : 0.f;
      unsigned short* base; int cc;
      if (col < Nh) { base = outL; cc = col; }
      else          { base = outR; cc = col - Nh; }
      int rb = row0 + wm * 128 + i * 16 + l4 * 4;
#pragma unroll
      for (int r = 0; r < 4; ++r) {
        int rr = rb + r;
        if (rr < M) base[(size_t)rr * Nh + cc] = f2bf(acc[i][j][r] + bv);
      }
    }
  }
}

// ---------------- Fused GATv2 edge kernel, depth-3 pipelined gathers ----------------
template <int H>
__global__ __launch_bounds__(256)
void gat_edge_k(const unsigned short* __restrict__ xl, const unsigned short* __restrict__ xr,
                const float* __restrict__ att, const float* __restrict__ bias,
                const int* __restrict__ csr, const int* __restrict__ offsets,
                unsigned short* __restrict__ out, int n, int relu) {
  int gw = (blockIdx.x * 256 + threadIdx.x) >> 6;
  int lane = threadIdx.x & 63;
  if (gw >= n * H) return;
  int node, head;
  if (H == 1) { node = gw; head = 0; }
  else        { node = gw >> 1; head = gw & 1; }
  const int W = H * 512;
  const size_t rowoff = (size_t)node * W + head * 512;
  const size_t choff = (size_t)head * 512 + (size_t)(lane * 8);

  float xrv[8], atv[8];
  {
    ushort8 u = *(const ushort8*)(xr + rowoff + lane * 8);
    const float* ap = att + head * 512 + lane * 8;
#pragma unroll
    for (int j = 0; j < 8; ++j) { xrv[j] = bf2f(u[j]); atv[j] = ap[j]; }
  }
  int p0 = offsets[node], p1 = offsets[node + 1];
  ushort8 u0 = *(const ushort8*)(xl + (size_t)csr[p0] * W + choff);
  ushort8 u1 = u0, u2 = u0;
  if (p0 + 1 < p1) u1 = *(const ushort8*)(xl + (size_t)csr[p0 + 1] * W + choff);
  if (p0 + 2 < p1) u2 = *(const ushort8*)(xl + (size_t)csr[p0 + 2] * W + choff);

  float m = -1e30f, l = 0.f;
  float acc[8];
#pragma unroll
  for (int j = 0; j < 8; ++j) acc[j] = 0.f;
  for (int p = p0; p < p1; ++p) {
    ushort8 u = u0;
    u0 = u1; u1 = u2;
    if (p + 3 < p1) u2 = *(const ushort8*)(xl + (size_t)csr[p + 3] * W + choff);
    float lv[8];
    float e = 0.f;
#pragma unroll
    for (int j = 0; j < 8; ++j) {
      lv[j] = bf2f(u[j]);
      float z = lv[j] + xrv[j];
      z = fmaxf(z, 0.f) + 0.2f * fminf(z, 0.f);
      e = fmaf(z, atv[j], e);
    }
#pragma unroll
    for (int off = 32; off > 0; off >>= 1) e += __shfl_xor(e, off, 64);
    float mn = fmaxf(m, e);
    float corr = __expf(m - mn);
    float w = __expf(e - mn);
    l = l * corr + w;
#pragma unroll
    for (int j = 0; j < 8; ++j) acc[j] = acc[j] * corr + w * lv[j];
    m = mn;
  }
  float inv = 1.f / (l * (float)(p1 - p0));
  const float* bp = bias + head * 512 + lane * 8;
  ushort8 o;
#pragma unroll
  for (int j = 0; j < 8; ++j) {
    float v = acc[j] * inv + bp[j];
    if (relu) v = fmaxf(v, 0.f);
    o[j] = f2bf(v);
  }
  *(ushort8*)(out + rowoff + lane * 8) = o;
}

// ---------------- fused head + gather: out = sigmoid(h[tidx]@Wh+bh), y[tidx] --------
__global__ void head_gather_k(const unsigned short* __restrict__ h, const float* __restrict__ Wh,
                   const float* __restrict__ bh, const float* __restrict__ y,
                   const int* __restrict__ tidx, float* __restrict__ out, int nt) {
  int gw = (blockIdx.x * 256 + threadIdx.x) >> 6;
  int lane = threadIdx.x & 63;
  if (gw >= nt) return;
  int j = tidx[gw];
  ushort8 u = *(const ushort8*)(h + (size_t)j * 512 + lane * 8);
  const float* wp = Wh + lane * 8;
  float s = 0.f;
#pragma unroll
  for (int q = 0; q < 8; ++q) s = fmaf(bf2f(u[q]), wp[q], s);
#pragma unroll
  for (int off = 32; off > 0; off >>= 1) s += __shfl_xor(s, off, 64);
  if (lane == 0) {
    out[gw] = 1.f / (1.f + __expf(-(s + bh[0])));
    out[nt + gw] = y[j];
  }
}

// ---------------- launch ----------------
extern "C" void kernel_launch(void* const* d_in, const int* in_sizes, int n_in,
                              void* d_out, int out_size, void* d_ws, size_t ws_size,
                              hipStream_t stream) {
  const float* x     = (const float*)d_in[0];
  const int*   ei    = (const int*)d_in[1];
  const float* y     = (const float*)d_in[2];
  const int*   tidx  = (const int*)d_in[3];
  const float* bn0_g = (const float*)d_in[4];
  const float* bn0_b = (const float*)d_in[5];
  const float* W1l   = (const float*)d_in[6];
  const float* W1r   = (const float*)d_in[7];
  const float* a1    = (const float*)d_in[8];
  const float* b1    = (const float*)d_in[9];
  const float* bn1_g = (const float*)d_in[10];
  const float* bn1_b = (const float*)d_in[11];
  const float* W2l   = (const float*)d_in[12];
  const float* W2r   = (const float*)d_in[13];
  const float* a2    = (const float*)d_in[14];
  const float* b2    = (const float*)d_in[15];
  const float* bn2_g = (const float*)d_in[16];
  const float* bn2_b = (const float*)d_in[17];
  const float* W3l   = (const float*)d_in[18];
  const float* W3r   = (const float*)d_in[19];
  const float* a3    = (const float*)d_in[20];
  const float* b3    = (const float*)d_in[21];
  const float* bn3_g = (const float*)d_in[22];
  const float* bn3_b = (const float*)d_in[23];
  const float* W4l   = (const float*)d_in[24];
  const float* W4r   = (const float*)d_in[25];
  const float* a4    = (const float*)d_in[26];
  const float* b4    = (const float*)d_in[27];
  const float* Wh    = (const float*)d_in[28];
  const float* bh    = (const float*)d_in[29];
  float* out = (float*)d_out;

  const int n   = in_sizes[2];      // 8000
  const int E   = in_sizes[1] / 2;  // 64000
  const int FIN = in_sizes[4];      // 3201
  const int NT  = in_sizes[3];      // 4000
  const int ET  = E + n;
  const int KP1 = 3328;             // pad to 52 K-tiles (even, for 8-phase)
  const int NY0 = 200;              // stats_convert y-blocks
  const int NYS = 160;              // col_stats y-blocks

  // ---- workspace layout ----
  unsigned short* us = (unsigned short*)d_ws;
  const size_t ABF_SZ = (size_t)n * KP1;
  unsigned short* Abf = us;
  unsigned short* hb  = us + ABF_SZ;
  unsigned short* xlb = hb + (size_t)n * 1024;
  unsigned short* xrb = xlb + (size_t)n * 1024;
  float* fp = (float*)(xrb + (size_t)n * 1024);
  float* biasb = fp;           fp += 2048;   // zeroed each launch
  float* coefA = fp;           fp += 3328;   // BN0 fold: row scale
  float* coefC = fp;           fp += 3328;   // BN0 fold: additive const
  float* aC    = fp;           fp += 1024;   // per-layer BN a (reused)
  float* cC    = fp;           fp += 1024;   // per-layer BN c (reused)
  int* deg     = (int*)fp;
  int* offsets = deg + n;
  int* cursor  = offsets + n + 1;
  int* csr     = cursor + n;
  unsigned short* W1T = hb;                          // [2048, KP1] combined Bt
  unsigned short* WT  = Abf + (size_t)n * 1024;      // layers 2-4 combined Bt
  // BN0 stats partials: live in hb region BEFORE wconv writes W1T there.
  float* P0a = (float*)hb;                   // [NY0][KP1]
  float* P0b = P0a + (size_t)NY0 * KP1;
  // BN1-3 stats partials: tail of Abf region (free after layer-1 GEMMs).
  float* Psa = (float*)(Abf + (size_t)n * 1024 + 8ull * 1024 * 1024);
  float* Psb = Psa + (size_t)NYS * 1024;

  // ---- init + CSR build ----
  const int kZeroCount = 2048;
  int zmax = n > kZeroCount ? n : kZeroCount;
  zero_k<<<(zmax + 255) / 256, 256, 0, stream>>>(biasb, kZeroCount, deg, n);
  deg_count_k<<<(E + 255) / 256, 256, 0, stream>>>(ei + E, deg, E);
  scan_k<<<1, 1024, 0, stream>>>(deg, offsets, cursor, n);
  csr_fill_k<<<(ET + 255) / 256, 256, 0, stream>>>(ei, ei + E, cursor, csr, E, n);

  float invM = 1.f / (float)n;

  // ---- BN0: fused stats (partials) + raw bf16 convert (single coalesced pass) ----
  {
    dim3 g((KP1 + 255) / 256, NY0);
    stats_convert_k<<<g, 256, 0, stream>>>(x, Abf, P0a, P0b, n, FIN, KP1);
    coef_k<<<(KP1 + 63) / 64, 256, 0, stream>>>(P0a, P0b, bn0_g, bn0_b,
                                                coefA, coefC, FIN, KP1, NY0, invM);
  }

  // ---- Layer 1 (H=2, K=3328 padded -> 2048 cols merged), BN0 folded -------
  {
    dim3 gw1(1024 / 32, KP1 / 32, 2);
    wconv_pair_k<<<gw1, 256, 0, stream>>>(W1l, W1r, W1T, FIN, 1024, KP1, coefA);
    dim3 gb(8, (FIN + 127) / 128);
    bias_fold_k<<<gb, 256, 0, stream>>>(W1l, W1r, coefC, biasb, FIN, 1024, 128);
    dim3 g(2048 / 256, (n + 255) / 256);   // 8 x 32 = 256 blocks, 1/CU
    gemm8p_k<<<g, 512, 0, stream>>>(Abf, W1T, xlb, xrb, biasb, n, 1024, KP1);
  }
  gat_edge_k<2><<<(n * 2 + 3) / 4, 256, 0, stream>>>(xlb, xrb, a1, b1, csr, offsets, hb, n, 0);
  {
    dim3 g(1024 / 256, NYS);
    col_stats_bf_k<<<g, 256, 0, stream>>>(hb, n, 1024, Psa, Psb);
    coef_k<<<1024 / 64, 256, 0, stream>>>(Psa, Psb, bn1_g, bn1_b, aC, cC, 1024, 1024, NYS, invM);
    bn_apply8_k<<<(int)(((size_t)n * 1024 / 8 + 255) / 256), 256, 0, stream>>>(
        hb, aC, cC, Abf, (size_t)n * 1024, 1024);
  }

  // ---- Layer 2 (K=1024 -> N=1024 combined) ----
  {
    dim3 gw2(512 / 32, 1024 / 32, 2);
    wconv_pair_k<<<gw2, 256, 0, stream>>>(W2l, W2r, WT, 1024, 512, 1024, nullptr);
    dim3 g(1024 / 256, (n + 127) / 128);   // 4 x 63 = 252 blocks
    gemm256_k<128><<<g, 512, 0, stream>>>(Abf, WT, xlb, xrb, nullptr, n, 512, 1024);
  }
  gat_edge_k<1><<<(n + 3) / 4, 256, 0, stream>>>(xlb, xrb, a2, b2, csr, offsets, hb, n, 0);
  {
    dim3 g(512 / 256, NYS);
    col_stats_bf_k<<<g, 256, 0, stream>>>(hb, n, 512, Psa, Psb);
    coef_k<<<512 / 64, 256, 0, stream>>>(Psa, Psb, bn2_g, bn2_b, aC, cC, 512, 512, NYS, invM);
    bn_apply8_k<<<(int)(((size_t)n * 512 / 8 + 255) / 256), 256, 0, stream>>>(
        hb, aC, cC, Abf, (size_t)n * 512, 512);
  }

  // ---- Layer 3 (K=512 -> N=1024 combined) ----
  {
    dim3 gw3(512 / 32, 512 / 32, 2);
    wconv_pair_k<<<gw3, 256, 0, stream>>>(W3l, W3r, WT, 512, 512, 512, nullptr);
    dim3 g(1024 / 256, (n + 127) / 128);
    gemm256_k<128><<<g, 512, 0, stream>>>(Abf, WT, xlb, xrb, nullptr, n, 512, 512);
  }
  gat_edge_k<1><<<(n + 3) / 4, 256, 0, stream>>>(xlb, xrb, a3, b3, csr, offsets, hb, n, 0);
  {
    dim3 g(512 / 256, NYS);
    col_stats_bf_k<<<g, 256, 0, stream>>>(hb, n, 512, Psa, Psb);
    coef_k<<<512 / 64, 256, 0, stream>>>(Psa, Psb, bn3_g, bn3_b, aC, cC, 512, 512, NYS, invM);
    bn_apply8_k<<<(int)(((size_t)n * 512 / 8 + 255) / 256), 256, 0, stream>>>(
        hb, aC, cC, Abf, (size_t)n * 512, 512);
  }

  // ---- Layer 4 (K=512 -> N=1024 combined), relu fused into edge kernel ----
  {
    dim3 gw4(512 / 32, 512 / 32, 2);
    wconv_pair_k<<<gw4, 256, 0, stream>>>(W4l, W4r, WT, 512, 512, 512, nullptr);
    dim3 g(1024 / 256, (n + 127) / 128);
    gemm256_k<128><<<g, 512, 0, stream>>>(Abf, WT, xlb, xrb, nullptr, n, 512, 512);
  }
  gat_edge_k<1><<<(n + 3) / 4, 256, 0, stream>>>(xlb, xrb, a4, b4, csr, offsets, hb, n, 1);

  // ---- fused head + gather (train rows only) ----
  head_gather_k<<<(NT + 3) / 4, 256, 0, stream>>>(hb, Wh, bh, y, tidx, out, NT);
}